// Round 3
// baseline (311.297 us; speedup 1.0000x reference)
//
#include <hip/hip_runtime.h>
#include <hip/hip_bf16.h>
#include <math.h>

#define N_PTS 4096
#define INV_SQRT2 0.70710678118654752440f

typedef float f32x4 __attribute__((ext_vector_type(4)));
typedef short s16x4 __attribute__((ext_vector_type(4)));
typedef short s16x8 __attribute__((ext_vector_type(8)));

__device__ inline short f2bf(float x) {
    __hip_bfloat16 h = __float2bfloat16(x);
    return __builtin_bit_cast(short, h);
}

// ---- 16x16x16 bf16 MFMA: builtin if present, else inline asm ----
#if defined(__has_builtin)
#  if __has_builtin(__builtin_amdgcn_mfma_f32_16x16x16bf16_1k)
#    define MFMA16(a, b, c) __builtin_amdgcn_mfma_f32_16x16x16bf16_1k((a), (b), (c), 0, 0, 0)
#    define HAVE_MFMA16 1
#  elif __has_builtin(__builtin_amdgcn_mfma_f32_16x16x16_bf16)
#    define MFMA16(a, b, c) __builtin_amdgcn_mfma_f32_16x16x16_bf16((a), (b), (c), 0, 0, 0)
#    define HAVE_MFMA16 1
#  endif
#endif
#ifndef HAVE_MFMA16
__device__ inline f32x4 mfma16_asm(s16x4 a, s16x4 b, f32x4 c) {
    asm volatile("s_nop 1\n\tv_mfma_f32_16x16x16_bf16 %0, %1, %2, %0"
                 : "+v"(c) : "v"(a), "v"(b));
    return c;
}
#  define MFMA16(a, b, c) mfma16_asm((a), (b), (c))
#endif

// ---------------------------------------------------------------------------
// Kernel A/D: 64->64->64 MLP with leaky relu + per-group partial stats.
// ---------------------------------------------------------------------------
__global__ __launch_bounds__(256) void mlp_gn_kernel(
    const float* __restrict__ inp,
    const float* __restrict__ W1, const float* __restrict__ b1,
    const float* __restrict__ W2, const float* __restrict__ b2,
    float* __restrict__ pre_out, float* __restrict__ partials)
{
    __shared__ float in_s[4][64];
    __shared__ float h1_s[4][64];
    __shared__ float red_s[4][8];

    const int tid = threadIdx.x;
    const int lane = tid & 63;
    const int wid = tid >> 6;
    const int n0 = blockIdx.x * 4;

    in_s[wid][lane] = inp[n0 * 64 + tid];
    __syncthreads();

    const int c = lane;
    float h = b1[c];
#pragma unroll
    for (int k4 = 0; k4 < 16; ++k4) {
        float4 wv = *(const float4*)&W1[c * 64 + k4 * 4];
        h = fmaf(in_s[wid][k4*4+0], wv.x, h);
        h = fmaf(in_s[wid][k4*4+1], wv.y, h);
        h = fmaf(in_s[wid][k4*4+2], wv.z, h);
        h = fmaf(in_s[wid][k4*4+3], wv.w, h);
    }
    h = (h >= 0.f) ? h : 0.2f * h;
    h1_s[wid][c] = h;
    __syncthreads();

    float g = b2[c];
#pragma unroll
    for (int k4 = 0; k4 < 16; ++k4) {
        float4 wv = *(const float4*)&W2[c * 64 + k4 * 4];
        g = fmaf(h1_s[wid][k4*4+0], wv.x, g);
        g = fmaf(h1_s[wid][k4*4+1], wv.y, g);
        g = fmaf(h1_s[wid][k4*4+2], wv.z, g);
        g = fmaf(h1_s[wid][k4*4+3], wv.w, g);
    }
    g = (g >= 0.f) ? g : 0.2f * g;
    pre_out[n0 * 64 + tid] = g;

    float v = g, v2 = g * g;
#pragma unroll
    for (int m = 1; m < 16; m <<= 1) {
        v  += __shfl_xor(v,  m, 64);
        v2 += __shfl_xor(v2, m, 64);
    }
    if ((lane & 15) == 0) {
        int grp = lane >> 4;
        red_s[wid][grp * 2 + 0] = v;
        red_s[wid][grp * 2 + 1] = v2;
    }
    __syncthreads();
    if (tid < 8) {
        int grp = tid >> 1, which = tid & 1;
        float s = red_s[0][grp*2+which] + red_s[1][grp*2+which]
                + red_s[2][grp*2+which] + red_s[3][grp*2+which];
        partials[blockIdx.x * 8 + grp * 2 + which] = s;
    }
}

// ---------------------------------------------------------------------------
// Kernel B/E: finalize group stats -> per-channel scale/shift.
// ---------------------------------------------------------------------------
__global__ __launch_bounds__(256) void finalize_kernel(
    const float* __restrict__ partials, int nblocks,
    const float* __restrict__ gw, const float* __restrict__ gb,
    float* __restrict__ ss)
{
    __shared__ float red[8][32];
    __shared__ float mean_s[4], inv_s[4];
    const int t = threadIdx.x;
    const int s = t >> 5, slot = t & 31;
    float acc = 0.f;
    for (int b = slot; b < nblocks; b += 32) acc += partials[b * 8 + s];
    red[s][slot] = acc;
    __syncthreads();
    if (t < 8) {
        float v = 0.f;
#pragma unroll
        for (int k = 0; k < 32; ++k) v += red[t][k];
        red[t][0] = v;
    }
    __syncthreads();
    if (t < 4) {
        float S = red[t * 2][0], SS = red[t * 2 + 1][0];
        const float cnt = (float)N_PTS * 16.f;
        float mean = S / cnt;
        float var = SS / cnt - mean * mean;
        mean_s[t] = mean;
        inv_s[t] = rsqrtf(var + 1e-5f);
    }
    __syncthreads();
    if (t < 64) {
        int grp = t >> 4;
        float sc = gw[t] * inv_s[grp];
        ss[t] = sc;
        ss[64 + t] = gb[t] - mean_s[grp] * sc;
    }
}

// ---------------------------------------------------------------------------
// Kernel: normalized features, bf16, TRANSPOSED: fn_t[h][j].
// ---------------------------------------------------------------------------
__global__ __launch_bounds__(256) void fnt_kernel(
    const float* __restrict__ f_pre, const float* __restrict__ ss,
    short* __restrict__ fn_t)
{
    const int h = blockIdx.x >> 4;
    const int j = ((blockIdx.x & 15) << 8) + threadIdx.x;
    float v = f_pre[j * 64 + h] * ss[h] + ss[64 + h];
    fn_t[h * 4096 + j] = f2bf(v);
}

// ---------------------------------------------------------------------------
// Prep: per-point scaled coords + normal (f32, padded) and bf16 {x,y,z,1}.
// ---------------------------------------------------------------------------
__global__ __launch_bounds__(256) void prep_kernel(
    const float* __restrict__ points, const float* __restrict__ nuv,
    float* __restrict__ ptn4, short* __restrict__ ptfeat4)
{
    const int j = blockIdx.x * 256 + threadIdx.x;
    float sx = points[j*3+0] * INV_SQRT2;
    float sy = points[j*3+1] * INV_SQRT2;
    float sz = points[j*3+2] * INV_SQRT2;
    float nx = nuv[j*9+0], ny = nuv[j*9+1], nz = nuv[j*9+2];
    *(float4*)&ptn4[j*8 + 0] = (float4){sx, sy, sz, 0.f};
    *(float4*)&ptn4[j*8 + 4] = (float4){nx, ny, nz, 0.f};
    s16x4 pf;
    pf[0] = f2bf(sx); pf[1] = f2bf(sy); pf[2] = f2bf(sz); pf[3] = f2bf(1.0f);
    *(s16x4*)&ptfeat4[j*4] = pf;
}

// ---------------------------------------------------------------------------
// Pairwise kernel: 3-MFMA chain, no relayout LDS.
// Block = 256 = 4 waves; wave wid owns i = blockIdx*4+wid; j tiled 64, sub 16.
//  MFMA1: C1[c-rows, j-cols] = coeff_i(16x16,K=4used) @ ptfeat[j]
//  per-lane (j=hl): s1,dot,w in f32 VALU; P = bf16(w*relu(C1)) (row8 = w)
//  MFMA2: Z[j-rows, h-cols] = P-as-A @ A2t-frag  (4 h-tiles)
//  MFMA3: acc[h',h] += fnT-frag @ reluZ-as-B ; diag(acc) = out.
// LDS: fn tile [64h][72sh rows=144B] + pts [64j][12f rows=48B], double-buffered.
// ---------------------------------------------------------------------------
__global__ __launch_bounds__(256) void pairwise_kernel(
    const float* __restrict__ nuv,
    const float* __restrict__ ptn4, const short* __restrict__ ptfeat4,
    const short* __restrict__ fn_t,
    const float* __restrict__ A1, const float* __restrict__ c1,
    const float* __restrict__ A2, const float* __restrict__ c2,
    float* __restrict__ out_raw)
{
    __shared__ short FS[2][64 * 72];   // fn tile, rows 144B  (18.0 KB)
    __shared__ float PS[2][64 * 12];   // pts+normal, rows 48B (6.0 KB)

    const int tid = threadIdx.x;
    const int l = tid & 63;
    const int wid = tid >> 6;
    const int g = l >> 4;
    const int hl = l & 15;
    const int i = blockIdx.x * 4 + wid;

    // ---- i-side (wave-uniform) ----
    float nv[9];
#pragma unroll
    for (int k = 0; k < 9; ++k) nv[k] = nuv[i*9+k];
    const float pix = ptn4[i*8+0], piy = ptn4[i*8+1], piz = ptn4[i*8+2];
    const float ni0 = nv[0], ni1 = nv[1], ni2 = nv[2];

    // coeff A-frag: lane(g=0,hl): row hl = [M[hl,0..2], c1'] ; row8=[0,0,0,1]
    s16x4 coefA = (s16x4){0,0,0,0};
    if (g == 0) {
        if (hl < 8) {
            float a0 = A1[hl*3+0], a1 = A1[hl*3+1], a2 = A1[hl*3+2];
            float m0 = a0*nv[0] + a1*nv[3] + a2*nv[6];
            float m1 = a0*nv[1] + a1*nv[4] + a2*nv[7];
            float m2 = a0*nv[2] + a1*nv[5] + a2*nv[8];
            float bb = c1[hl] - (m0*pix + m1*piy + m2*piz);
            coefA[0] = f2bf(m0); coefA[1] = f2bf(m1);
            coefA[2] = f2bf(m2); coefA[3] = f2bf(bb);
        } else if (hl == 8) {
            coefA[3] = f2bf(1.0f);
        }
    }

    // A2t B-frags: lane(g,hl): B[k=4g+r][h=ht*16+hl] = A2[h][c]|c2|0
    s16x4 A2sB[4];
#pragma unroll
    for (int ht = 0; ht < 4; ++ht) {
        const int h = ht * 16 + hl;
        s16x4 v;
#pragma unroll
        for (int r = 0; r < 4; ++r) {
            const int cc = 4 * g + r;
            float val = (cc < 8) ? A2[h*8 + cc] : ((cc == 8) ? c2[h] : 0.f);
            v[r] = f2bf(val);
        }
        A2sB[ht] = v;
    }

    f32x4 acc[4];
#pragma unroll
    for (int ht = 0; ht < 4; ++ht) acc[ht] = (f32x4){0.f, 0.f, 0.f, 0.f};

    // ---- staging helper (all 256 threads) ----
    auto stage = [&](int buf, int jc) {
        // fn tile: 64 rows x 128B ; thread t: row t>>2, 32B chunk t&3
        const int row = tid >> 2, ch = tid & 3;
        const short* src = fn_t + row * 4096 + jc * 64 + ch * 16;
        s16x8 a = *(const s16x8*)src;
        s16x8 b = *(const s16x8*)(src + 8);
        short* dst = &FS[buf][row * 72 + ch * 16];
        *(s16x8*)dst = a;
        *(s16x8*)(dst + 8) = b;
        // pts: 64 rows x 32B ; threads 0..127: row t>>1, 16B half t&1
        if (tid < 128) {
            const int r2 = tid >> 1, hf = tid & 1;
            float4 v = *(const float4*)&ptn4[(jc * 64 + r2) * 8 + hf * 4];
            *(float4*)&PS[buf][r2 * 12 + hf * 4] = v;
        }
    };

    stage(0, 0);

    for (int jc = 0; jc < 64; ++jc) {
        const int cur = jc & 1;
        __syncthreads();
        if (jc < 63) stage(cur ^ 1, jc + 1);

#pragma unroll
        for (int jsub = 0; jsub < 4; ++jsub) {
            const int j16 = jsub * 16 + hl;

            // MFMA1 B-frag: point features (g==0 lanes only)
            s16x4 bp = (s16x4){0,0,0,0};
            if (g == 0) bp = *(const s16x4*)&ptfeat4[(jc * 64 + j16) * 4];
            f32x4 C1 = MFMA16(coefA, bp, ((f32x4){0.f,0.f,0.f,0.f}));

            // per-lane f32 geometry for j = jc*64 + j16
            float4 pj = *(const float4*)&PS[cur][j16 * 12];
            float4 nj = *(const float4*)&PS[cur][j16 * 12 + 4];
            float dx = pj.x - pix, dy = pj.y - piy, dz = pj.z - piz;
            float s1 = dx*dx + dy*dy + dz*dz;
            float dot = ni0*nj.x + ni1*nj.y + ni2*nj.z;
            float t2 = 2.f - dot;
            float d2 = s1 * t2 * t2;
            float w = __expf(-d2);

            // P = bf16(w * relu(C1))  (row 8 -> w via coeff trick)
            s16x4 P;
            P[0] = f2bf(fmaxf(C1[0], 0.f) * w);
            P[1] = f2bf(fmaxf(C1[1], 0.f) * w);
            P[2] = f2bf(fmaxf(C1[2], 0.f) * w);
            P[3] = f2bf(fmaxf(C1[3], 0.f) * w);

#pragma unroll
            for (int ht = 0; ht < 4; ++ht) {
                f32x4 Z = MFMA16(P, A2sB[ht], ((f32x4){0.f,0.f,0.f,0.f}));
                s16x4 az;
                az[0] = f2bf(fmaxf(Z[0], 0.f));
                az[1] = f2bf(fmaxf(Z[1], 0.f));
                az[2] = f2bf(fmaxf(Z[2], 0.f));
                az[3] = f2bf(fmaxf(Z[3], 0.f));
                const s16x4 fnf = *(const s16x4*)&FS[cur][(ht*16 + hl) * 72 + jsub * 16 + 4 * g];
                acc[ht] = MFMA16(fnf, az, acc[ht]);
            }
        }
    }

    asm volatile("s_nop 7\n\ts_nop 7" ::: );

    // diag extraction: lane with g == hl>>2 holds diag element (reg r = hl&3)
    if (g == (hl >> 2)) {
        const int r = hl & 3;
#pragma unroll
        for (int ht = 0; ht < 4; ++ht) {
            float v = (r == 0) ? acc[ht][0] : (r == 1) ? acc[ht][1]
                    : (r == 2) ? acc[ht][2] : acc[ht][3];
            out_raw[i * 64 + ht * 16 + hl] = v;
        }
    }
}

// ---------------------------------------------------------------------------
// Kernel F: apply output groupnorm affine.
// ---------------------------------------------------------------------------
__global__ __launch_bounds__(256) void apply_kernel(
    const float* __restrict__ pre, const float* __restrict__ ss,
    float* __restrict__ out)
{
    int idx = blockIdx.x * 256 + threadIdx.x;
    int c = idx & 63;
    out[idx] = pre[idx] * ss[c] + ss[64 + c];
}

// ---------------------------------------------------------------------------
extern "C" void kernel_launch(void* const* d_in, const int* in_sizes, int n_in,
                              void* d_out, int out_size, void* d_ws, size_t ws_size,
                              hipStream_t stream) {
    const float* points   = (const float*)d_in[0];
    const float* nuv      = (const float*)d_in[1];
    const float* features = (const float*)d_in[2];
    const float* W_in1    = (const float*)d_in[3];
    const float* b_in1    = (const float*)d_in[4];
    const float* W_in2    = (const float*)d_in[5];
    const float* b_in2    = (const float*)d_in[6];
    const float* gn_in_w  = (const float*)d_in[7];
    const float* gn_in_b  = (const float*)d_in[8];
    const float* A1       = (const float*)d_in[9];
    const float* c1       = (const float*)d_in[10];
    const float* A2       = (const float*)d_in[11];
    const float* c2       = (const float*)d_in[12];
    const float* W_out1   = (const float*)d_in[13];
    const float* b_out1   = (const float*)d_in[14];
    const float* W_out2   = (const float*)d_in[15];
    const float* b_out2   = (const float*)d_in[16];
    const float* gn_out_w = (const float*)d_in[17];
    const float* gn_out_b = (const float*)d_in[18];

    char* ws = (char*)d_ws;
    float* f_pre    = (float*)(ws + 0);            // 1 MB (aliased with g_pre)
    float* g_pre    = (float*)(ws + 0);
    float* out_raw  = (float*)(ws + 1048576);      // 1 MB
    short* fn_t     = (short*)(ws + 2097152);      // 512 KB
    float* ptn4     = (float*)(ws + 2621440);      // 128 KB
    short* ptfeat4  = (short*)(ws + 2752512);      // 32 KB
    float* part_in  = (float*)(ws + 2785280);      // 32 KB
    float* part_out = (float*)(ws + 2818048);      // 32 KB
    float* ss_in    = (float*)(ws + 2850816);      // 512 B
    float* ss_out   = (float*)(ws + 2851328);      // 512 B

    float* outp = (float*)d_out;

    prep_kernel<<<16, 256, 0, stream>>>(points, nuv, ptn4, ptfeat4);

    mlp_gn_kernel<<<1024, 256, 0, stream>>>(features, W_in1, b_in1, W_in2, b_in2,
                                            f_pre, part_in);
    finalize_kernel<<<1, 256, 0, stream>>>(part_in, 1024, gn_in_w, gn_in_b, ss_in);
    fnt_kernel<<<1024, 256, 0, stream>>>(f_pre, ss_in, fn_t);

    pairwise_kernel<<<1024, 256, 0, stream>>>(nuv, ptn4, ptfeat4, fn_t,
                                              A1, c1, A2, c2, out_raw);

    mlp_gn_kernel<<<1024, 256, 0, stream>>>(out_raw, W_out1, b_out1, W_out2, b_out2,
                                            g_pre, part_out);
    finalize_kernel<<<1, 256, 0, stream>>>(part_out, 1024, gn_out_w, gn_out_b, ss_out);

    apply_kernel<<<1024, 256, 0, stream>>>(g_pre, ss_out, outp);
}

// Round 5
// 264.699 us; speedup vs baseline: 1.1760x; 1.1760x over previous
//
#include <hip/hip_runtime.h>
#include <hip/hip_bf16.h>
#include <math.h>

#define N_PTS 4096
#define INV_SQRT2 0.70710678118654752440f

typedef float f32x4 __attribute__((ext_vector_type(4)));
typedef short s16x4 __attribute__((ext_vector_type(4)));
typedef short s16x8 __attribute__((ext_vector_type(8)));

__device__ inline short f2bf(float x) {
    __hip_bfloat16 h = __float2bfloat16(x);
    return __builtin_bit_cast(short, h);
}

// ---- 16x16x16 bf16 MFMA: builtin if present, else inline asm ----
#if defined(__has_builtin)
#  if __has_builtin(__builtin_amdgcn_mfma_f32_16x16x16bf16_1k)
#    define MFMA16(a, b, c) __builtin_amdgcn_mfma_f32_16x16x16bf16_1k((a), (b), (c), 0, 0, 0)
#    define HAVE_MFMA16 1
#  elif __has_builtin(__builtin_amdgcn_mfma_f32_16x16x16_bf16)
#    define MFMA16(a, b, c) __builtin_amdgcn_mfma_f32_16x16x16_bf16((a), (b), (c), 0, 0, 0)
#    define HAVE_MFMA16 1
#  endif
#endif
#ifndef HAVE_MFMA16
__device__ inline f32x4 mfma16_asm(s16x4 a, s16x4 b, f32x4 c) {
    asm volatile("s_nop 1\n\tv_mfma_f32_16x16x16_bf16 %0, %1, %2, %0"
                 : "+v"(c) : "v"(a), "v"(b));
    return c;
}
#  define MFMA16(a, b, c) mfma16_asm((a), (b), (c))
#endif

// ---------------------------------------------------------------------------
// Kernel A/D: 64->64->64 MLP with leaky relu + per-group partial stats.
// ---------------------------------------------------------------------------
__global__ __launch_bounds__(256) void mlp_gn_kernel(
    const float* __restrict__ inp,
    const float* __restrict__ W1, const float* __restrict__ b1,
    const float* __restrict__ W2, const float* __restrict__ b2,
    float* __restrict__ pre_out, float* __restrict__ partials)
{
    __shared__ float in_s[4][64];
    __shared__ float h1_s[4][64];
    __shared__ float red_s[4][8];

    const int tid = threadIdx.x;
    const int lane = tid & 63;
    const int wid = tid >> 6;
    const int n0 = blockIdx.x * 4;

    in_s[wid][lane] = inp[n0 * 64 + tid];
    __syncthreads();

    const int c = lane;
    float h = b1[c];
#pragma unroll
    for (int k4 = 0; k4 < 16; ++k4) {
        float4 wv = *(const float4*)&W1[c * 64 + k4 * 4];
        h = fmaf(in_s[wid][k4*4+0], wv.x, h);
        h = fmaf(in_s[wid][k4*4+1], wv.y, h);
        h = fmaf(in_s[wid][k4*4+2], wv.z, h);
        h = fmaf(in_s[wid][k4*4+3], wv.w, h);
    }
    h = (h >= 0.f) ? h : 0.2f * h;
    h1_s[wid][c] = h;
    __syncthreads();

    float g = b2[c];
#pragma unroll
    for (int k4 = 0; k4 < 16; ++k4) {
        float4 wv = *(const float4*)&W2[c * 64 + k4 * 4];
        g = fmaf(h1_s[wid][k4*4+0], wv.x, g);
        g = fmaf(h1_s[wid][k4*4+1], wv.y, g);
        g = fmaf(h1_s[wid][k4*4+2], wv.z, g);
        g = fmaf(h1_s[wid][k4*4+3], wv.w, g);
    }
    g = (g >= 0.f) ? g : 0.2f * g;
    pre_out[n0 * 64 + tid] = g;

    float v = g, v2 = g * g;
#pragma unroll
    for (int m = 1; m < 16; m <<= 1) {
        v  += __shfl_xor(v,  m, 64);
        v2 += __shfl_xor(v2, m, 64);
    }
    if ((lane & 15) == 0) {
        int grp = lane >> 4;
        red_s[wid][grp * 2 + 0] = v;
        red_s[wid][grp * 2 + 1] = v2;
    }
    __syncthreads();
    if (tid < 8) {
        int grp = tid >> 1, which = tid & 1;
        float s = red_s[0][grp*2+which] + red_s[1][grp*2+which]
                + red_s[2][grp*2+which] + red_s[3][grp*2+which];
        partials[blockIdx.x * 8 + grp * 2 + which] = s;
    }
}

// ---------------------------------------------------------------------------
// Kernel B/E: finalize group stats -> per-channel scale/shift.
// ---------------------------------------------------------------------------
__global__ __launch_bounds__(256) void finalize_kernel(
    const float* __restrict__ partials, int nblocks,
    const float* __restrict__ gw, const float* __restrict__ gb,
    float* __restrict__ ss)
{
    __shared__ float red[8][32];
    __shared__ float mean_s[4], inv_s[4];
    const int t = threadIdx.x;
    const int s = t >> 5, slot = t & 31;
    float acc = 0.f;
    for (int b = slot; b < nblocks; b += 32) acc += partials[b * 8 + s];
    red[s][slot] = acc;
    __syncthreads();
    if (t < 8) {
        float v = 0.f;
#pragma unroll
        for (int k = 0; k < 32; ++k) v += red[t][k];
        red[t][0] = v;
    }
    __syncthreads();
    if (t < 4) {
        float S = red[t * 2][0], SS = red[t * 2 + 1][0];
        const float cnt = (float)N_PTS * 16.f;
        float mean = S / cnt;
        float var = SS / cnt - mean * mean;
        mean_s[t] = mean;
        inv_s[t] = rsqrtf(var + 1e-5f);
    }
    __syncthreads();
    if (t < 64) {
        int grp = t >> 4;
        float sc = gw[t] * inv_s[grp];
        ss[t] = sc;
        ss[64 + t] = gb[t] - mean_s[grp] * sc;
    }
}

// ---------------------------------------------------------------------------
// Kernel: normalized features bf16 transposed fn_t[h][j]; also (blocks 0..15)
// per-point scaled coords + normal, f32 padded (prep fused in).
// ---------------------------------------------------------------------------
__global__ __launch_bounds__(256) void fnt_kernel(
    const float* __restrict__ f_pre, const float* __restrict__ ss,
    short* __restrict__ fn_t,
    const float* __restrict__ points, const float* __restrict__ nuv,
    float* __restrict__ ptn4)
{
    const int h = blockIdx.x >> 4;
    const int j = ((blockIdx.x & 15) << 8) + threadIdx.x;
    float v = f_pre[j * 64 + h] * ss[h] + ss[64 + h];
    fn_t[h * 4096 + j] = f2bf(v);

    if (blockIdx.x < 16) {
        const int p = blockIdx.x * 256 + threadIdx.x;
        float sx = points[p*3+0] * INV_SQRT2;
        float sy = points[p*3+1] * INV_SQRT2;
        float sz = points[p*3+2] * INV_SQRT2;
        float nx = nuv[p*9+0], ny = nuv[p*9+1], nz = nuv[p*9+2];
        *(float4*)&ptn4[p*8 + 0] = (float4){sx, sy, sz, 0.f};
        *(float4*)&ptn4[p*8 + 4] = (float4){nx, ny, nz, 0.f};
    }
}

// ---------------------------------------------------------------------------
// Pairwise kernel.
// Block = 256 = 4 waves; wave wid owns i = blockIdx*4+wid; j tiled by 64.
//  phase1 (lane=j): geometry in f32, 8 cuts, w; P row (12 shorts, 24B) -> P_s.
//  phase2 per jsub(4): A-frag = b64 from P_s;
//    MFMA2 16x16x16: Z[j,h] = P @ A2t   (K=16, slots 0..7 cuts, 8=w->c2)
//    az = bf16(relu(Z)); MFMA3: acc[h',h] += fnT @ az ; diag(acc) = out.
// FS fn tile [h][72sh], XOR-swizzled 8B units, double-buffered.
// PS pts+normals [j][12f], double-buffered.  P_s per-wave (wave-local, no
// barrier needed: same-wave LDS RAW ordered by compiler waitcnts).
// ---------------------------------------------------------------------------
__global__ __launch_bounds__(256) void pairwise_kernel(
    const float* __restrict__ nuv,
    const float* __restrict__ ptn4,
    const short* __restrict__ fn_t,
    const float* __restrict__ A1, const float* __restrict__ c1,
    const float* __restrict__ A2, const float* __restrict__ c2,
    float* __restrict__ out_raw)
{
    __shared__ __align__(16) short FS[2][64 * 72];   // 18.0 KB
    __shared__ __align__(16) float PS[2][64 * 12];   //  6.0 KB
    __shared__ __align__(16) short P_s[4][64 * 12];  //  6.0 KB (per-wave)

    const int tid = threadIdx.x;
    const int l = tid & 63;
    const int wid = tid >> 6;
    const int g = l >> 4;
    const int hl = l & 15;
    const int i = blockIdx.x * 4 + wid;

    // ---- i-side (wave-uniform) ----
    float nv[9];
#pragma unroll
    for (int k = 0; k < 9; ++k) nv[k] = nuv[i*9+k];
    const float pix = ptn4[i*8+0], piy = ptn4[i*8+1], piz = ptn4[i*8+2];

    float a1v[8][3], c1v[8];
#pragma unroll
    for (int cc = 0; cc < 8; ++cc) {
        a1v[cc][0] = A1[cc*3+0]; a1v[cc][1] = A1[cc*3+1]; a1v[cc][2] = A1[cc*3+2];
        c1v[cc] = c1[cc];
    }

    // A2t B-frags (K=16): lane(g,hl): B[k=4g+r][h=ht*16+hl] = A2[h][k]|c2|0
    s16x4 A2sB[4];
#pragma unroll
    for (int ht = 0; ht < 4; ++ht) {
        const int h = ht * 16 + hl;
        s16x4 v;
#pragma unroll
        for (int r = 0; r < 4; ++r) {
            const int cc = 4 * g + r;
            float val = (cc < 8) ? A2[h*8 + cc] : ((cc == 8) ? c2[h] : 0.f);
            v[r] = f2bf(val);
        }
        A2sB[ht] = v;
    }

    f32x4 acc[4];
#pragma unroll
    for (int ht = 0; ht < 4; ++ht) acc[ht] = (f32x4){0.f, 0.f, 0.f, 0.f};

    // ---- staging: fn tile with XOR swizzle + pts tile (all 256 threads) ----
    auto stage = [&](int buf, int jc) {
        const int h = tid >> 2, q4 = tid & 3, hx = h & 15, hb = h * 72;
        const short* src = fn_t + h * 4096 + jc * 64 + q4 * 16;
        s16x8 u0 = *(const s16x8*)src;
        s16x8 u1 = *(const s16x8*)(src + 8);
        *(s16x4*)&FS[buf][hb + (((q4*4+0) ^ hx) << 2)] = __builtin_shufflevector(u0, u0, 0,1,2,3);
        *(s16x4*)&FS[buf][hb + (((q4*4+1) ^ hx) << 2)] = __builtin_shufflevector(u0, u0, 4,5,6,7);
        *(s16x4*)&FS[buf][hb + (((q4*4+2) ^ hx) << 2)] = __builtin_shufflevector(u1, u1, 0,1,2,3);
        *(s16x4*)&FS[buf][hb + (((q4*4+3) ^ hx) << 2)] = __builtin_shufflevector(u1, u1, 4,5,6,7);
        if (tid < 128) {
            const int r2 = tid >> 1, hf = tid & 1;
            float4 v = *(const float4*)&ptn4[(jc * 64 + r2) * 8 + hf * 4];
            *(float4*)&PS[buf][r2 * 12 + hf * 4] = v;
        }
    };

    stage(0, 0);

    for (int jc = 0; jc < 64; ++jc) {
        const int cur = jc & 1;
        __syncthreads();                       // FS/PS[cur] ready; [cur^1] free
        if (jc < 63) stage(cur ^ 1, jc + 1);   // overlaps with compute below

        // ---- phase 1: lane l owns j = jc*64 + l ----
        {
            float4 pj = *(const float4*)&PS[cur][l * 12];
            float4 nj = *(const float4*)&PS[cur][l * 12 + 4];
            float dx = pj.x - pix, dy = pj.y - piy, dz = pj.z - piz;
            float s1 = dx*dx + dy*dy + dz*dz;
            float dot = nv[0]*nj.x + nv[1]*nj.y + nv[2]*nj.z;
            float t2 = 2.f - dot;
            float d2 = s1 * t2 * t2;
            float w = __expf(-d2);
            float X0 = nv[0]*dx + nv[1]*dy + nv[2]*dz;
            float X1 = nv[3]*dx + nv[4]*dy + nv[5]*dz;
            float X2 = nv[6]*dx + nv[7]*dy + nv[8]*dz;

            s16x4 r0, r1, r2;
#pragma unroll
            for (int cc = 0; cc < 8; ++cc) {
                float hv = fmaf(X0, a1v[cc][0],
                           fmaf(X1, a1v[cc][1],
                           fmaf(X2, a1v[cc][2], c1v[cc])));
                hv = fmaxf(hv, 0.f) * w;
                if (cc < 4) r0[cc] = f2bf(hv); else r1[cc-4] = f2bf(hv);
            }
            r2 = (s16x4){0,0,0,0};
            r2[0] = f2bf(w);
            short* rp = &P_s[wid][l * 12];
            *(s16x4*)(rp + 0) = r0;
            *(s16x4*)(rp + 4) = r1;
            *(s16x4*)(rp + 8) = r2;
        }
        // no barrier: P_s is wave-local; compiler orders same-wave LDS RAW.

        // ---- phase 2 ----
#pragma unroll
        for (int jsub = 0; jsub < 4; ++jsub) {
            const s16x4 Af = *(const s16x4*)&P_s[wid][(jsub*16 + hl) * 12 + 4 * g];
#pragma unroll
            for (int ht = 0; ht < 4; ++ht) {
                f32x4 Z = MFMA16(Af, A2sB[ht], ((f32x4){0.f,0.f,0.f,0.f}));
                s16x4 az;
                az[0] = f2bf(fmaxf(Z[0], 0.f));
                az[1] = f2bf(fmaxf(Z[1], 0.f));
                az[2] = f2bf(fmaxf(Z[2], 0.f));
                az[3] = f2bf(fmaxf(Z[3], 0.f));
                const s16x4 fnf = *(const s16x4*)&FS[cur][(ht*16 + hl) * 72 + (((jsub*4 + g) ^ hl) << 2)];
                acc[ht] = MFMA16(fnf, az, acc[ht]);
            }
        }
    }

    asm volatile("s_nop 7\n\ts_nop 7" ::: );

    // diag extraction: lane with g == hl>>2 holds diag element (reg r = hl&3)
    if (g == (hl >> 2)) {
        const int r = hl & 3;
#pragma unroll
        for (int ht = 0; ht < 4; ++ht) {
            float v = (r == 0) ? acc[ht][0] : (r == 1) ? acc[ht][1]
                    : (r == 2) ? acc[ht][2] : acc[ht][3];
            out_raw[i * 64 + ht * 16 + hl] = v;
        }
    }
}

// ---------------------------------------------------------------------------
// Kernel F: apply output groupnorm affine.
// ---------------------------------------------------------------------------
__global__ __launch_bounds__(256) void apply_kernel(
    const float* __restrict__ pre, const float* __restrict__ ss,
    float* __restrict__ out)
{
    int idx = blockIdx.x * 256 + threadIdx.x;
    int c = idx & 63;
    out[idx] = pre[idx] * ss[c] + ss[64 + c];
}

// ---------------------------------------------------------------------------
extern "C" void kernel_launch(void* const* d_in, const int* in_sizes, int n_in,
                              void* d_out, int out_size, void* d_ws, size_t ws_size,
                              hipStream_t stream) {
    const float* points   = (const float*)d_in[0];
    const float* nuv      = (const float*)d_in[1];
    const float* features = (const float*)d_in[2];
    const float* W_in1    = (const float*)d_in[3];
    const float* b_in1    = (const float*)d_in[4];
    const float* W_in2    = (const float*)d_in[5];
    const float* b_in2    = (const float*)d_in[6];
    const float* gn_in_w  = (const float*)d_in[7];
    const float* gn_in_b  = (const float*)d_in[8];
    const float* A1       = (const float*)d_in[9];
    const float* c1       = (const float*)d_in[10];
    const float* A2       = (const float*)d_in[11];
    const float* c2       = (const float*)d_in[12];
    const float* W_out1   = (const float*)d_in[13];
    const float* b_out1   = (const float*)d_in[14];
    const float* W_out2   = (const float*)d_in[15];
    const float* b_out2   = (const float*)d_in[16];
    const float* gn_out_w = (const float*)d_in[17];
    const float* gn_out_b = (const float*)d_in[18];

    char* ws = (char*)d_ws;
    float* f_pre    = (float*)(ws + 0);            // 1 MB (aliased with g_pre)
    float* g_pre    = (float*)(ws + 0);
    float* out_raw  = (float*)(ws + 1048576);      // 1 MB
    short* fn_t     = (short*)(ws + 2097152);      // 512 KB
    float* ptn4     = (float*)(ws + 2621440);      // 128 KB
    float* part_in  = (float*)(ws + 2785280);      // 32 KB
    float* part_out = (float*)(ws + 2818048);      // 32 KB
    float* ss_in    = (float*)(ws + 2850816);      // 512 B
    float* ss_out   = (float*)(ws + 2851328);      // 512 B

    float* outp = (float*)d_out;

    mlp_gn_kernel<<<1024, 256, 0, stream>>>(features, W_in1, b_in1, W_in2, b_in2,
                                            f_pre, part_in);
    finalize_kernel<<<1, 256, 0, stream>>>(part_in, 1024, gn_in_w, gn_in_b, ss_in);
    fnt_kernel<<<1024, 256, 0, stream>>>(f_pre, ss_in, fn_t, points, nuv, ptn4);

    pairwise_kernel<<<1024, 256, 0, stream>>>(nuv, ptn4, fn_t,
                                              A1, c1, A2, c2, out_raw);

    mlp_gn_kernel<<<1024, 256, 0, stream>>>(out_raw, W_out1, b_out1, W_out2, b_out2,
                                            g_pre, part_out);
    finalize_kernel<<<1, 256, 0, stream>>>(part_out, 1024, gn_out_w, gn_out_b, ss_out);

    apply_kernel<<<1024, 256, 0, stream>>>(g_pre, ss_out, outp);
}

// Round 6
// 219.713 us; speedup vs baseline: 1.4168x; 1.2047x over previous
//
#include <hip/hip_runtime.h>
#include <hip/hip_bf16.h>
#include <math.h>

#define N_PTS 4096
#define INV_SQRT2 0.70710678118654752440f

typedef float f32x4 __attribute__((ext_vector_type(4)));
typedef short s16x4 __attribute__((ext_vector_type(4)));
typedef short s16x8 __attribute__((ext_vector_type(8)));

__device__ inline short f2bf(float x) {
    __hip_bfloat16 h = __float2bfloat16(x);
    return __builtin_bit_cast(short, h);
}

// Truncating pack: 2 f32 -> u32 holding {bf16(hi), bf16(lo)}. One v_perm_b32.
// Valid for non-negative values (truncation toward zero); bias <= 2^-8 rel,
// absorbed by the final GroupNorm (net_out is positively homogeneous, zero biases).
__device__ inline unsigned pk_trunc(float hi, float lo) {
    return __builtin_amdgcn_perm(__builtin_bit_cast(unsigned, hi),
                                 __builtin_bit_cast(unsigned, lo),
                                 0x07060302u);
}

// ---- 16x16x16 bf16 MFMA: builtin if present, else inline asm ----
#if defined(__has_builtin)
#  if __has_builtin(__builtin_amdgcn_mfma_f32_16x16x16bf16_1k)
#    define MFMA16(a, b, c) __builtin_amdgcn_mfma_f32_16x16x16bf16_1k((a), (b), (c), 0, 0, 0)
#    define HAVE_MFMA16 1
#  elif __has_builtin(__builtin_amdgcn_mfma_f32_16x16x16_bf16)
#    define MFMA16(a, b, c) __builtin_amdgcn_mfma_f32_16x16x16_bf16((a), (b), (c), 0, 0, 0)
#    define HAVE_MFMA16 1
#  endif
#endif
#ifndef HAVE_MFMA16
__device__ inline f32x4 mfma16_asm(s16x4 a, s16x4 b, f32x4 c) {
    asm volatile("s_nop 1\n\tv_mfma_f32_16x16x16_bf16 %0, %1, %2, %0"
                 : "+v"(c) : "v"(a), "v"(b));
    return c;
}
#  define MFMA16(a, b, c) mfma16_asm((a), (b), (c))
#endif

// ---------------------------------------------------------------------------
// Kernel A/D: 64->64->64 MLP with leaky relu + per-group partial stats.
// ---------------------------------------------------------------------------
__global__ __launch_bounds__(256) void mlp_gn_kernel(
    const float* __restrict__ inp,
    const float* __restrict__ W1, const float* __restrict__ b1,
    const float* __restrict__ W2, const float* __restrict__ b2,
    float* __restrict__ pre_out, float* __restrict__ partials)
{
    __shared__ float in_s[4][64];
    __shared__ float h1_s[4][64];
    __shared__ float red_s[4][8];

    const int tid = threadIdx.x;
    const int lane = tid & 63;
    const int wid = tid >> 6;
    const int n0 = blockIdx.x * 4;

    in_s[wid][lane] = inp[n0 * 64 + tid];
    __syncthreads();

    const int c = lane;
    float h = b1[c];
#pragma unroll
    for (int k4 = 0; k4 < 16; ++k4) {
        float4 wv = *(const float4*)&W1[c * 64 + k4 * 4];
        h = fmaf(in_s[wid][k4*4+0], wv.x, h);
        h = fmaf(in_s[wid][k4*4+1], wv.y, h);
        h = fmaf(in_s[wid][k4*4+2], wv.z, h);
        h = fmaf(in_s[wid][k4*4+3], wv.w, h);
    }
    h = (h >= 0.f) ? h : 0.2f * h;
    h1_s[wid][c] = h;
    __syncthreads();

    float g = b2[c];
#pragma unroll
    for (int k4 = 0; k4 < 16; ++k4) {
        float4 wv = *(const float4*)&W2[c * 64 + k4 * 4];
        g = fmaf(h1_s[wid][k4*4+0], wv.x, g);
        g = fmaf(h1_s[wid][k4*4+1], wv.y, g);
        g = fmaf(h1_s[wid][k4*4+2], wv.z, g);
        g = fmaf(h1_s[wid][k4*4+3], wv.w, g);
    }
    g = (g >= 0.f) ? g : 0.2f * g;
    pre_out[n0 * 64 + tid] = g;

    float v = g, v2 = g * g;
#pragma unroll
    for (int m = 1; m < 16; m <<= 1) {
        v  += __shfl_xor(v,  m, 64);
        v2 += __shfl_xor(v2, m, 64);
    }
    if ((lane & 15) == 0) {
        int grp = lane >> 4;
        red_s[wid][grp * 2 + 0] = v;
        red_s[wid][grp * 2 + 1] = v2;
    }
    __syncthreads();
    if (tid < 8) {
        int grp = tid >> 1, which = tid & 1;
        float s = red_s[0][grp*2+which] + red_s[1][grp*2+which]
                + red_s[2][grp*2+which] + red_s[3][grp*2+which];
        partials[blockIdx.x * 8 + grp * 2 + which] = s;
    }
}

// ---------------------------------------------------------------------------
// Kernel B/E: finalize group stats -> per-channel scale/shift.
// ---------------------------------------------------------------------------
__global__ __launch_bounds__(256) void finalize_kernel(
    const float* __restrict__ partials, int nblocks,
    const float* __restrict__ gw, const float* __restrict__ gb,
    float* __restrict__ ss)
{
    __shared__ float red[8][32];
    __shared__ float mean_s[4], inv_s[4];
    const int t = threadIdx.x;
    const int s = t >> 5, slot = t & 31;
    float acc = 0.f;
    for (int b = slot; b < nblocks; b += 32) acc += partials[b * 8 + s];
    red[s][slot] = acc;
    __syncthreads();
    if (t < 8) {
        float v = 0.f;
#pragma unroll
        for (int k = 0; k < 32; ++k) v += red[t][k];
        red[t][0] = v;
    }
    __syncthreads();
    if (t < 4) {
        float S = red[t * 2][0], SS = red[t * 2 + 1][0];
        const float cnt = (float)N_PTS * 16.f;
        float mean = S / cnt;
        float var = SS / cnt - mean * mean;
        mean_s[t] = mean;
        inv_s[t] = rsqrtf(var + 1e-5f);
    }
    __syncthreads();
    if (t < 64) {
        int grp = t >> 4;
        float sc = gw[t] * inv_s[grp];
        ss[t] = sc;
        ss[64 + t] = gb[t] - mean_s[grp] * sc;
    }
}

// ---------------------------------------------------------------------------
// Kernel: normalized features bf16 transposed fn_t[h][j]; also (blocks 0..15)
// per-point scaled coords + normal, f32 padded (prep fused in).
// ---------------------------------------------------------------------------
__global__ __launch_bounds__(256) void fnt_kernel(
    const float* __restrict__ f_pre, const float* __restrict__ ss,
    short* __restrict__ fn_t,
    const float* __restrict__ points, const float* __restrict__ nuv,
    float* __restrict__ ptn4)
{
    const int h = blockIdx.x >> 4;
    const int j = ((blockIdx.x & 15) << 8) + threadIdx.x;
    float v = f_pre[j * 64 + h] * ss[h] + ss[64 + h];
    fn_t[h * 4096 + j] = f2bf(v);

    if (blockIdx.x < 16) {
        const int p = blockIdx.x * 256 + threadIdx.x;
        float sx = points[p*3+0] * INV_SQRT2;
        float sy = points[p*3+1] * INV_SQRT2;
        float sz = points[p*3+2] * INV_SQRT2;
        float nx = nuv[p*9+0], ny = nuv[p*9+1], nz = nuv[p*9+2];
        *(float4*)&ptn4[p*8 + 0] = (float4){sx, sy, sz, 0.f};
        *(float4*)&ptn4[p*8 + 4] = (float4){nx, ny, nz, 0.f};
    }
}

// ---------------------------------------------------------------------------
// Pairwise kernel.
// Block = 256 = 4 waves; wave wid owns i = blockIdx*4+wid; j tiled by 64.
//  phase1 (lane=j): geometry in f32 (cuts via per-i M = A1*nuv_i, 3 FMA each),
//    P row = {w*relu(cut_0..7), w} packed to bf16 via v_perm truncation -> P_s.
//  phase2 per jsub(4): A-frag = b64 from P_s;
//    MFMA2 16x16x16: Z[j,h] = P @ A2t   (K=16, slots 0..7 cuts, 8=w->c2)
//    az = trunc-pack(relu(Z)); MFMA3: acc[h',h] += fnT @ az ; diag = out.
// FS fn tile [h][72sh], XOR-swizzled 8B units, double-buffered.
// PS pts+normals [j][12f], double-buffered.  P_s per-wave (wave-local).
// ---------------------------------------------------------------------------
__global__ __launch_bounds__(256) void pairwise_kernel(
    const float* __restrict__ nuv,
    const float* __restrict__ ptn4,
    const short* __restrict__ fn_t,
    const float* __restrict__ A1, const float* __restrict__ c1,
    const float* __restrict__ A2, const float* __restrict__ c2,
    float* __restrict__ out_raw)
{
    __shared__ __align__(16) short FS[2][64 * 72];   // 18.0 KB
    __shared__ __align__(16) float PS[2][64 * 12];   //  6.0 KB
    __shared__ __align__(16) short P_s[4][64 * 12];  //  6.0 KB (per-wave)

    const int tid = threadIdx.x;
    const int l = tid & 63;
    const int wid = tid >> 6;
    const int g = l >> 4;
    const int hl = l & 15;
    const int i = blockIdx.x * 4 + wid;

    // ---- i-side (wave-uniform) ----
    float nv[9];
#pragma unroll
    for (int k = 0; k < 9; ++k) nv[k] = nuv[i*9+k];
    const float pix = ptn4[i*8+0], piy = ptn4[i*8+1], piz = ptn4[i*8+2];
    const float ni0 = nv[0], ni1 = nv[1], ni2 = nv[2];

    // per-i cut coefficients: M[c] = A1[c] (row) * nuv_i (3x3) ; cut = M.d + c1
    float m0[8], m1[8], m2[8], c1v[8];
#pragma unroll
    for (int cc = 0; cc < 8; ++cc) {
        float a0 = A1[cc*3+0], a1 = A1[cc*3+1], a2 = A1[cc*3+2];
        m0[cc] = a0*nv[0] + a1*nv[3] + a2*nv[6];
        m1[cc] = a0*nv[1] + a1*nv[4] + a2*nv[7];
        m2[cc] = a0*nv[2] + a1*nv[5] + a2*nv[8];
        c1v[cc] = c1[cc];
    }

    // A2t B-frags (K=16): lane(g,hl): B[k=4g+r][h=ht*16+hl] = A2[h][k]|c2|0
    s16x4 A2sB[4];
#pragma unroll
    for (int ht = 0; ht < 4; ++ht) {
        const int h = ht * 16 + hl;
        s16x4 v;
#pragma unroll
        for (int r = 0; r < 4; ++r) {
            const int cc = 4 * g + r;
            float val = (cc < 8) ? A2[h*8 + cc] : ((cc == 8) ? c2[h] : 0.f);
            v[r] = f2bf(val);
        }
        A2sB[ht] = v;
    }

    f32x4 acc[4];
#pragma unroll
    for (int ht = 0; ht < 4; ++ht) acc[ht] = (f32x4){0.f, 0.f, 0.f, 0.f};

    // ---- staging: fn tile with XOR swizzle + pts tile (all 256 threads) ----
    auto stage = [&](int buf, int jc) {
        const int h = tid >> 2, q4 = tid & 3, hx = h & 15, hb = h * 72;
        const short* src = fn_t + h * 4096 + jc * 64 + q4 * 16;
        s16x8 u0 = *(const s16x8*)src;
        s16x8 u1 = *(const s16x8*)(src + 8);
        *(s16x4*)&FS[buf][hb + (((q4*4+0) ^ hx) << 2)] = __builtin_shufflevector(u0, u0, 0,1,2,3);
        *(s16x4*)&FS[buf][hb + (((q4*4+1) ^ hx) << 2)] = __builtin_shufflevector(u0, u0, 4,5,6,7);
        *(s16x4*)&FS[buf][hb + (((q4*4+2) ^ hx) << 2)] = __builtin_shufflevector(u1, u1, 0,1,2,3);
        *(s16x4*)&FS[buf][hb + (((q4*4+3) ^ hx) << 2)] = __builtin_shufflevector(u1, u1, 4,5,6,7);
        if (tid < 128) {
            const int r2 = tid >> 1, hf = tid & 1;
            float4 v = *(const float4*)&ptn4[(jc * 64 + r2) * 8 + hf * 4];
            *(float4*)&PS[buf][r2 * 12 + hf * 4] = v;
        }
    };

    stage(0, 0);

    for (int jc = 0; jc < 64; ++jc) {
        const int cur = jc & 1;
        __syncthreads();                       // FS/PS[cur] ready; [cur^1] free
        if (jc < 63) stage(cur ^ 1, jc + 1);   // overlaps with compute below

        // ---- phase 1: lane l owns j = jc*64 + l ----
        {
            float4 pj = *(const float4*)&PS[cur][l * 12];
            float4 nj = *(const float4*)&PS[cur][l * 12 + 4];
            float dx = pj.x - pix, dy = pj.y - piy, dz = pj.z - piz;
            float s1 = dx*dx + dy*dy + dz*dz;
            float dot = ni0*nj.x + ni1*nj.y + ni2*nj.z;
            float t2 = 2.f - dot;
            float d2 = s1 * t2 * t2;
            float w = __expf(-d2);

            float hv[8];
#pragma unroll
            for (int cc = 0; cc < 8; ++cc) {
                float t = fmaf(dx, m0[cc], fmaf(dy, m1[cc], fmaf(dz, m2[cc], c1v[cc])));
                hv[cc] = fmaxf(t, 0.f) * w;
            }
            // truncating packs (1 v_perm per pair; all values >= 0)
            int2 ra, rb, rc;
            ra.x = (int)pk_trunc(hv[1], hv[0]);
            ra.y = (int)pk_trunc(hv[3], hv[2]);
            rb.x = (int)pk_trunc(hv[5], hv[4]);
            rb.y = (int)pk_trunc(hv[7], hv[6]);
            rc.x = (int)(__builtin_bit_cast(unsigned, w) >> 16);  // {w, 0}
            rc.y = 0;
            short* rp = &P_s[wid][l * 12];
            *(int2*)(rp + 0) = ra;
            *(int2*)(rp + 4) = rb;
            *(int2*)(rp + 8) = rc;
        }
        // no barrier: P_s is wave-local; compiler orders same-wave LDS RAW.

        // ---- phase 2 ----
#pragma unroll
        for (int jsub = 0; jsub < 4; ++jsub) {
            const s16x4 Af = *(const s16x4*)&P_s[wid][(jsub*16 + hl) * 12 + 4 * g];
#pragma unroll
            for (int ht = 0; ht < 4; ++ht) {
                f32x4 Z = MFMA16(Af, A2sB[ht], ((f32x4){0.f,0.f,0.f,0.f}));
                int2 av;
                av.x = (int)pk_trunc(fmaxf(Z[1], 0.f), fmaxf(Z[0], 0.f));
                av.y = (int)pk_trunc(fmaxf(Z[3], 0.f), fmaxf(Z[2], 0.f));
                s16x4 az = __builtin_bit_cast(s16x4, av);
                const s16x4 fnf = *(const s16x4*)&FS[cur][(ht*16 + hl) * 72 + (((jsub*4 + g) ^ hl) << 2)];
                acc[ht] = MFMA16(fnf, az, acc[ht]);
            }
        }
    }

    asm volatile("s_nop 7\n\ts_nop 7" ::: );

    // diag extraction: lane with g == hl>>2 holds diag element (reg r = hl&3)
    if (g == (hl >> 2)) {
        const int r = hl & 3;
#pragma unroll
        for (int ht = 0; ht < 4; ++ht) {
            float v = (r == 0) ? acc[ht][0] : (r == 1) ? acc[ht][1]
                    : (r == 2) ? acc[ht][2] : acc[ht][3];
            out_raw[i * 64 + ht * 16 + hl] = v;
        }
    }
}

// ---------------------------------------------------------------------------
// Kernel F: apply output groupnorm affine.
// ---------------------------------------------------------------------------
__global__ __launch_bounds__(256) void apply_kernel(
    const float* __restrict__ pre, const float* __restrict__ ss,
    float* __restrict__ out)
{
    int idx = blockIdx.x * 256 + threadIdx.x;
    int c = idx & 63;
    out[idx] = pre[idx] * ss[c] + ss[64 + c];
}

// ---------------------------------------------------------------------------
extern "C" void kernel_launch(void* const* d_in, const int* in_sizes, int n_in,
                              void* d_out, int out_size, void* d_ws, size_t ws_size,
                              hipStream_t stream) {
    const float* points   = (const float*)d_in[0];
    const float* nuv      = (const float*)d_in[1];
    const float* features = (const float*)d_in[2];
    const float* W_in1    = (const float*)d_in[3];
    const float* b_in1    = (const float*)d_in[4];
    const float* W_in2    = (const float*)d_in[5];
    const float* b_in2    = (const float*)d_in[6];
    const float* gn_in_w  = (const float*)d_in[7];
    const float* gn_in_b  = (const float*)d_in[8];
    const float* A1       = (const float*)d_in[9];
    const float* c1       = (const float*)d_in[10];
    const float* A2       = (const float*)d_in[11];
    const float* c2       = (const float*)d_in[12];
    const float* W_out1   = (const float*)d_in[13];
    const float* b_out1   = (const float*)d_in[14];
    const float* W_out2   = (const float*)d_in[15];
    const float* b_out2   = (const float*)d_in[16];
    const float* gn_out_w = (const float*)d_in[17];
    const float* gn_out_b = (const float*)d_in[18];

    char* ws = (char*)d_ws;
    float* f_pre    = (float*)(ws + 0);            // 1 MB (aliased with g_pre)
    float* g_pre    = (float*)(ws + 0);
    float* out_raw  = (float*)(ws + 1048576);      // 1 MB
    short* fn_t     = (short*)(ws + 2097152);      // 512 KB
    float* ptn4     = (float*)(ws + 2621440);      // 128 KB
    float* part_in  = (float*)(ws + 2785280);      // 32 KB
    float* part_out = (float*)(ws + 2818048);      // 32 KB
    float* ss_in    = (float*)(ws + 2850816);      // 512 B
    float* ss_out   = (float*)(ws + 2851328);      // 512 B

    float* outp = (float*)d_out;

    mlp_gn_kernel<<<1024, 256, 0, stream>>>(features, W_in1, b_in1, W_in2, b_in2,
                                            f_pre, part_in);
    finalize_kernel<<<1, 256, 0, stream>>>(part_in, 1024, gn_in_w, gn_in_b, ss_in);
    fnt_kernel<<<1024, 256, 0, stream>>>(f_pre, ss_in, fn_t, points, nuv, ptn4);

    pairwise_kernel<<<1024, 256, 0, stream>>>(nuv, ptn4, fn_t,
                                              A1, c1, A2, c2, out_raw);

    mlp_gn_kernel<<<1024, 256, 0, stream>>>(out_raw, W_out1, b_out1, W_out2, b_out2,
                                            g_pre, part_out);
    finalize_kernel<<<1, 256, 0, stream>>>(part_out, 1024, gn_out_w, gn_out_b, ss_out);

    apply_kernel<<<1024, 256, 0, stream>>>(g_pre, ss_out, outp);
}

// Round 7
// 216.378 us; speedup vs baseline: 1.4387x; 1.0154x over previous
//
#include <hip/hip_runtime.h>
#include <hip/hip_bf16.h>
#include <math.h>

#define N_PTS 4096
#define NT 32                     // j-tiles per block after the x2 j-split
#define INV_SQRT2 0.70710678118654752440f

typedef float f32x4 __attribute__((ext_vector_type(4)));
typedef short s16x4 __attribute__((ext_vector_type(4)));
typedef short s16x8 __attribute__((ext_vector_type(8)));

__device__ inline short f2bf(float x) {
    __hip_bfloat16 h = __float2bfloat16(x);
    return __builtin_bit_cast(short, h);
}

// Truncating pack: 2 f32 -> u32 holding {bf16(hi), bf16(lo)}. One v_perm_b32.
// Valid for non-negative values; bias <= 2^-8 rel, absorbed by final GroupNorm.
__device__ inline unsigned pk_trunc(float hi, float lo) {
    return __builtin_amdgcn_perm(__builtin_bit_cast(unsigned, hi),
                                 __builtin_bit_cast(unsigned, lo),
                                 0x07060302u);
}

// ---- 16x16x16 bf16 MFMA: builtin if present, else inline asm ----
#if defined(__has_builtin)
#  if __has_builtin(__builtin_amdgcn_mfma_f32_16x16x16bf16_1k)
#    define MFMA16(a, b, c) __builtin_amdgcn_mfma_f32_16x16x16bf16_1k((a), (b), (c), 0, 0, 0)
#    define HAVE_MFMA16 1
#  elif __has_builtin(__builtin_amdgcn_mfma_f32_16x16x16_bf16)
#    define MFMA16(a, b, c) __builtin_amdgcn_mfma_f32_16x16x16_bf16((a), (b), (c), 0, 0, 0)
#    define HAVE_MFMA16 1
#  endif
#endif
#ifndef HAVE_MFMA16
__device__ inline f32x4 mfma16_asm(s16x4 a, s16x4 b, f32x4 c) {
    asm volatile("s_nop 1\n\tv_mfma_f32_16x16x16_bf16 %0, %1, %2, %0"
                 : "+v"(c) : "v"(a), "v"(b));
    return c;
}
#  define MFMA16(a, b, c) mfma16_asm((a), (b), (c))
#endif

#if defined(__has_builtin) && __has_builtin(__builtin_amdgcn_global_load_lds)
#  define HAVE_GLDS 1
#endif

// ---------------------------------------------------------------------------
// Kernel A/D: 64->64->64 MLP with leaky relu + per-group partial stats.
// inp2 (optional): second partial-sum buffer added on load (fused j-split reduce).
// ---------------------------------------------------------------------------
__global__ __launch_bounds__(256) void mlp_gn_kernel(
    const float* __restrict__ inp, const float* __restrict__ inp2,
    const float* __restrict__ W1, const float* __restrict__ b1,
    const float* __restrict__ W2, const float* __restrict__ b2,
    float* __restrict__ pre_out, float* __restrict__ partials)
{
    __shared__ float in_s[4][64];
    __shared__ float h1_s[4][64];
    __shared__ float red_s[4][8];

    const int tid = threadIdx.x;
    const int lane = tid & 63;
    const int wid = tid >> 6;
    const int n0 = blockIdx.x * 4;

    float xin = inp[n0 * 64 + tid];
    if (inp2) xin += inp2[n0 * 64 + tid];
    in_s[wid][lane] = xin;
    __syncthreads();

    const int c = lane;
    float h = b1[c];
#pragma unroll
    for (int k4 = 0; k4 < 16; ++k4) {
        float4 wv = *(const float4*)&W1[c * 64 + k4 * 4];
        h = fmaf(in_s[wid][k4*4+0], wv.x, h);
        h = fmaf(in_s[wid][k4*4+1], wv.y, h);
        h = fmaf(in_s[wid][k4*4+2], wv.z, h);
        h = fmaf(in_s[wid][k4*4+3], wv.w, h);
    }
    h = (h >= 0.f) ? h : 0.2f * h;
    h1_s[wid][c] = h;
    __syncthreads();

    float g = b2[c];
#pragma unroll
    for (int k4 = 0; k4 < 16; ++k4) {
        float4 wv = *(const float4*)&W2[c * 64 + k4 * 4];
        g = fmaf(h1_s[wid][k4*4+0], wv.x, g);
        g = fmaf(h1_s[wid][k4*4+1], wv.y, g);
        g = fmaf(h1_s[wid][k4*4+2], wv.z, g);
        g = fmaf(h1_s[wid][k4*4+3], wv.w, g);
    }
    g = (g >= 0.f) ? g : 0.2f * g;
    pre_out[n0 * 64 + tid] = g;

    float v = g, v2 = g * g;
#pragma unroll
    for (int m = 1; m < 16; m <<= 1) {
        v  += __shfl_xor(v,  m, 64);
        v2 += __shfl_xor(v2, m, 64);
    }
    if ((lane & 15) == 0) {
        int grp = lane >> 4;
        red_s[wid][grp * 2 + 0] = v;
        red_s[wid][grp * 2 + 1] = v2;
    }
    __syncthreads();
    if (tid < 8) {
        int grp = tid >> 1, which = tid & 1;
        float s = red_s[0][grp*2+which] + red_s[1][grp*2+which]
                + red_s[2][grp*2+which] + red_s[3][grp*2+which];
        partials[blockIdx.x * 8 + grp * 2 + which] = s;
    }
}

// ---------------------------------------------------------------------------
// Kernel B/E: finalize group stats -> per-channel scale/shift.
// ---------------------------------------------------------------------------
__global__ __launch_bounds__(256) void finalize_kernel(
    const float* __restrict__ partials, int nblocks,
    const float* __restrict__ gw, const float* __restrict__ gb,
    float* __restrict__ ss)
{
    __shared__ float red[8][32];
    __shared__ float mean_s[4], inv_s[4];
    const int t = threadIdx.x;
    const int s = t >> 5, slot = t & 31;
    float acc = 0.f;
    for (int b = slot; b < nblocks; b += 32) acc += partials[b * 8 + s];
    red[s][slot] = acc;
    __syncthreads();
    if (t < 8) {
        float v = 0.f;
#pragma unroll
        for (int k = 0; k < 32; ++k) v += red[t][k];
        red[t][0] = v;
    }
    __syncthreads();
    if (t < 4) {
        float S = red[t * 2][0], SS = red[t * 2 + 1][0];
        const float cnt = (float)N_PTS * 16.f;
        float mean = S / cnt;
        float var = SS / cnt - mean * mean;
        mean_s[t] = mean;
        inv_s[t] = rsqrtf(var + 1e-5f);
    }
    __syncthreads();
    if (t < 64) {
        int grp = t >> 4;
        float sc = gw[t] * inv_s[grp];
        ss[t] = sc;
        ss[64 + t] = gb[t] - mean_s[grp] * sc;
    }
}

// ---------------------------------------------------------------------------
// Kernel: normalized features bf16, stored PRE-SWIZZLED per 64-j tile so the
// pairwise kernel can global_load_lds them linearly (m173 pattern):
//   fn_sw[tile][h][u][e] = fn[h][tile*64 + 4*(u ^ (h&15)) + e]
// Also (blocks 0..15) per-point scaled coords + normal, f32 padded.
// ---------------------------------------------------------------------------
__global__ __launch_bounds__(256) void fnt_kernel(
    const float* __restrict__ f_pre, const float* __restrict__ ss,
    short* __restrict__ fn_sw,
    const float* __restrict__ points, const float* __restrict__ nuv,
    float* __restrict__ ptn4)
{
    const int h = blockIdx.x >> 4;
    const int j = ((blockIdx.x & 15) << 8) + threadIdx.x;
    float v = f_pre[j * 64 + h] * ss[h] + ss[64 + h];
    const int t = j >> 6, jj = j & 63, c = jj >> 2, e = jj & 3;
    const int u = c ^ (h & 15);
    fn_sw[t * 4096 + h * 64 + u * 4 + e] = f2bf(v);

    if (blockIdx.x < 16) {
        const int p = blockIdx.x * 256 + threadIdx.x;
        float sx = points[p*3+0] * INV_SQRT2;
        float sy = points[p*3+1] * INV_SQRT2;
        float sz = points[p*3+2] * INV_SQRT2;
        float nx = nuv[p*9+0], ny = nuv[p*9+1], nz = nuv[p*9+2];
        *(float4*)&ptn4[p*8 + 0] = (float4){sx, sy, sz, 0.f};
        *(float4*)&ptn4[p*8 + 4] = (float4){nx, ny, nz, 0.f};
    }
}

// ---------------------------------------------------------------------------
// Pairwise kernel, j-split x2: block (ig, jh) handles i = ig*4+wid over the
// j range [jh*2048, jh*2048+2048), 32 tiles of 64. Partial sums -> out_part.
//  phase1 (lane=j): geometry f32 (register-prefetched pts), P -> P_s (LDS).
//  phase2 per jsub: MFMA2 (Z = P @ A2t, K=16), relu+trunc-pack, MFMA3
//    (acc += fnT @ az), diag(acc) = output row i.
// FS fn tile: LINEAR LDS filled by async global_load_lds from pre-swizzled
// fn_sw (2 x 16B per thread, zero repack). Double-buffered.
// ---------------------------------------------------------------------------
__global__ __launch_bounds__(256) void pairwise_kernel(
    const float* __restrict__ nuv,
    const float* __restrict__ ptn4,
    const short* __restrict__ fn_sw,
    const float* __restrict__ A1, const float* __restrict__ c1,
    const float* __restrict__ A2, const float* __restrict__ c2,
    float* __restrict__ out_part)
{
    __shared__ __align__(16) short FS[2][4096];      // 16.0 KB (64h x 64sh x dbuf)
    __shared__ __align__(16) short P_s[4][64*12+16]; //  6.1 KB (per-wave, +pad)

    const int tid = threadIdx.x;
    const int l = tid & 63;
    const int wid = tid >> 6;
    const int g = l >> 4;
    const int hl = l & 15;
    const int ig = blockIdx.x >> 1;
    const int jh = blockIdx.x & 1;
    const int i = ig * 4 + wid;
    const int jt0 = jh * NT;                 // first tile index for this block

    // ---- i-side (wave-uniform) ----
    float nv[9];
#pragma unroll
    for (int k = 0; k < 9; ++k) nv[k] = nuv[i*9+k];
    const float pix = ptn4[i*8+0], piy = ptn4[i*8+1], piz = ptn4[i*8+2];
    const float ni0 = nv[0], ni1 = nv[1], ni2 = nv[2];

    // per-i cut coefficients: M[c] = A1[c] (row) * nuv_i ; cut = M.d + c1
    float m0[8], m1[8], m2[8], c1v[8];
#pragma unroll
    for (int cc = 0; cc < 8; ++cc) {
        float a0 = A1[cc*3+0], a1 = A1[cc*3+1], a2 = A1[cc*3+2];
        m0[cc] = a0*nv[0] + a1*nv[3] + a2*nv[6];
        m1[cc] = a0*nv[1] + a1*nv[4] + a2*nv[7];
        m2[cc] = a0*nv[2] + a1*nv[5] + a2*nv[8];
        c1v[cc] = c1[cc];
    }

    // A2t B-frags (K=16): lane(g,hl): B[k=4g+r][h=ht*16+hl] = A2[h][k]|c2|0
    s16x4 A2sB[4];
#pragma unroll
    for (int ht = 0; ht < 4; ++ht) {
        const int h = ht * 16 + hl;
        s16x4 v;
#pragma unroll
        for (int r = 0; r < 4; ++r) {
            const int cc = 4 * g + r;
            float val = (cc < 8) ? A2[h*8 + cc] : ((cc == 8) ? c2[h] : 0.f);
            v[r] = f2bf(val);
        }
        A2sB[ht] = v;
    }

    f32x4 acc[4];
#pragma unroll
    for (int ht = 0; ht < 4; ++ht) acc[ht] = (f32x4){0.f, 0.f, 0.f, 0.f};

    // ---- async staging of the pre-swizzled fn tile (linear copy) ----
    auto stage = [&](int buf, int t) {
        const short* src = fn_sw + (size_t)(jt0 + t) * 4096;
#ifdef HAVE_GLDS
        const short* s0 = src + wid * 1024 + l * 8;          // lane*16B
        short* d0 = &FS[buf][wid * 1024];                    // wave-uniform base
        __builtin_amdgcn_global_load_lds((const unsigned int*)s0,
                                         (unsigned int*)d0, 16, 0, 0);
        __builtin_amdgcn_global_load_lds((const unsigned int*)(s0 + 512),
                                         (unsigned int*)(d0 + 512), 16, 0, 0);
#else
        s16x8 a = *(const s16x8*)(src + tid * 16);
        s16x8 b = *(const s16x8*)(src + tid * 16 + 8);
        *(s16x8*)&FS[buf][tid * 16] = a;
        *(s16x8*)&FS[buf][tid * 16 + 8] = b;
#endif
    };

    // register prefetch of j-side points/normals (T14 issue-early)
    const float* pbase = ptn4 + (size_t)jh * 2048 * 8;
    float4 pj_c = *(const float4*)&pbase[l * 8];
    float4 nj_c = *(const float4*)&pbase[l * 8 + 4];
    stage(0, 0);

    for (int t = 0; t < NT; ++t) {
        const int cur = t & 1;
        __syncthreads();                       // FS[cur] staged; FS[cur^1] free
        if (t < NT - 1) stage(cur ^ 1, t + 1); // async, drains at next barrier

        // issue next tile's point loads (consumed next iteration)
        const int tn = (t + 1) & (NT - 1);
        float4 pj_n = *(const float4*)&pbase[(tn * 64 + l) * 8];
        float4 nj_n = *(const float4*)&pbase[(tn * 64 + l) * 8 + 4];

        // ---- phase 1: lane l owns j = jh*2048 + t*64 + l ----
        {
            float dx = pj_c.x - pix, dy = pj_c.y - piy, dz = pj_c.z - piz;
            float s1 = dx*dx + dy*dy + dz*dz;
            float dot = ni0*nj_c.x + ni1*nj_c.y + ni2*nj_c.z;
            float t2 = 2.f - dot;
            float d2 = s1 * t2 * t2;
            float w = __expf(-d2);

            float hv[8];
#pragma unroll
            for (int cc = 0; cc < 8; ++cc) {
                float tt = fmaf(dx, m0[cc], fmaf(dy, m1[cc], fmaf(dz, m2[cc], c1v[cc])));
                hv[cc] = fmaxf(tt, 0.f) * w;
            }
            int2 ra, rb, rc;
            ra.x = (int)pk_trunc(hv[1], hv[0]);
            ra.y = (int)pk_trunc(hv[3], hv[2]);
            rb.x = (int)pk_trunc(hv[5], hv[4]);
            rb.y = (int)pk_trunc(hv[7], hv[6]);
            rc.x = (int)(__builtin_bit_cast(unsigned, w) >> 16);  // {w, 0}
            rc.y = 0;
            short* rp = &P_s[wid][l * 12];
            *(int2*)(rp + 0) = ra;
            *(int2*)(rp + 4) = rb;
            *(int2*)(rp + 8) = rc;
        }
        // no barrier: P_s is wave-local; compiler orders same-wave LDS RAW.

        // ---- phase 2 ----
#pragma unroll
        for (int jsub = 0; jsub < 4; ++jsub) {
            const s16x4 Af = *(const s16x4*)&P_s[wid][(jsub*16 + hl) * 12 + 4 * g];
#pragma unroll
            for (int ht = 0; ht < 4; ++ht) {
                f32x4 Z = MFMA16(Af, A2sB[ht], ((f32x4){0.f,0.f,0.f,0.f}));
                int2 av;
                av.x = (int)pk_trunc(fmaxf(Z[1], 0.f), fmaxf(Z[0], 0.f));
                av.y = (int)pk_trunc(fmaxf(Z[3], 0.f), fmaxf(Z[2], 0.f));
                s16x4 az = __builtin_bit_cast(s16x4, av);
                const s16x4 fnf = *(const s16x4*)&FS[cur][(ht*16 + hl) * 64 + (((jsub*4 + g) ^ hl) << 2)];
                acc[ht] = MFMA16(fnf, az, acc[ht]);
            }
        }

        pj_c = pj_n; nj_c = nj_n;
    }

    asm volatile("s_nop 7\n\ts_nop 7" ::: );

    // diag extraction: lane with g == hl>>2 holds diag element (reg r = hl&3)
    if (g == (hl >> 2)) {
        const int r = hl & 3;
#pragma unroll
        for (int ht = 0; ht < 4; ++ht) {
            float v = (r == 0) ? acc[ht][0] : (r == 1) ? acc[ht][1]
                    : (r == 2) ? acc[ht][2] : acc[ht][3];
            out_part[(size_t)jh * (N_PTS * 64) + i * 64 + ht * 16 + hl] = v;
        }
    }
}

// ---------------------------------------------------------------------------
// Kernel F: apply output groupnorm affine.
// ---------------------------------------------------------------------------
__global__ __launch_bounds__(256) void apply_kernel(
    const float* __restrict__ pre, const float* __restrict__ ss,
    float* __restrict__ out)
{
    int idx = blockIdx.x * 256 + threadIdx.x;
    int c = idx & 63;
    out[idx] = pre[idx] * ss[c] + ss[64 + c];
}

// ---------------------------------------------------------------------------
extern "C" void kernel_launch(void* const* d_in, const int* in_sizes, int n_in,
                              void* d_out, int out_size, void* d_ws, size_t ws_size,
                              hipStream_t stream) {
    const float* points   = (const float*)d_in[0];
    const float* nuv      = (const float*)d_in[1];
    const float* features = (const float*)d_in[2];
    const float* W_in1    = (const float*)d_in[3];
    const float* b_in1    = (const float*)d_in[4];
    const float* W_in2    = (const float*)d_in[5];
    const float* b_in2    = (const float*)d_in[6];
    const float* gn_in_w  = (const float*)d_in[7];
    const float* gn_in_b  = (const float*)d_in[8];
    const float* A1       = (const float*)d_in[9];
    const float* c1       = (const float*)d_in[10];
    const float* A2       = (const float*)d_in[11];
    const float* c2       = (const float*)d_in[12];
    const float* W_out1   = (const float*)d_in[13];
    const float* b_out1   = (const float*)d_in[14];
    const float* W_out2   = (const float*)d_in[15];
    const float* b_out2   = (const float*)d_in[16];
    const float* gn_out_w = (const float*)d_in[17];
    const float* gn_out_b = (const float*)d_in[18];

    char* ws = (char*)d_ws;
    float* out_part = (float*)(ws + 0);            // 2 MB (2 x 4096 x 64 f32)
    float* f_pre    = (float*)(ws + 2097152);      // 1 MB (dead after fnt)
    float* g_pre    = (float*)(ws + 2097152);      // alias, liveness-disjoint
    short* fn_sw    = (short*)(ws + 3145728);      // 512 KB (pre-swizzled bf16)
    float* ptn4     = (float*)(ws + 3670016);      // 128 KB
    float* part_in  = (float*)(ws + 3801088);      // 32 KB
    float* part_out = (float*)(ws + 3833856);      // 32 KB
    float* ss_in    = (float*)(ws + 3866624);      // 512 B
    float* ss_out   = (float*)(ws + 3867136);      // 512 B

    float* outp = (float*)d_out;

    mlp_gn_kernel<<<1024, 256, 0, stream>>>(features, nullptr, W_in1, b_in1,
                                            W_in2, b_in2, f_pre, part_in);
    finalize_kernel<<<1, 256, 0, stream>>>(part_in, 1024, gn_in_w, gn_in_b, ss_in);
    fnt_kernel<<<1024, 256, 0, stream>>>(f_pre, ss_in, fn_sw, points, nuv, ptn4);

    pairwise_kernel<<<2048, 256, 0, stream>>>(nuv, ptn4, fn_sw,
                                              A1, c1, A2, c2, out_part);

    // net_out MLP with fused j-split reduction (out_part half0 + half1)
    mlp_gn_kernel<<<1024, 256, 0, stream>>>(out_part, out_part + N_PTS * 64,
                                            W_out1, b_out1, W_out2, b_out2,
                                            g_pre, part_out);
    finalize_kernel<<<1, 256, 0, stream>>>(part_out, 1024, gn_out_w, gn_out_b, ss_out);

    apply_kernel<<<1024, 256, 0, stream>>>(g_pre, ss_out, outp);
}

// Round 8
// 174.695 us; speedup vs baseline: 1.7819x; 1.2386x over previous
//
#include <hip/hip_runtime.h>
#include <hip/hip_bf16.h>
#include <math.h>

#define N_PTS 4096
#define INV_SQRT2 0.70710678118654752440f

typedef float f32x4 __attribute__((ext_vector_type(4)));
typedef short s16x4 __attribute__((ext_vector_type(4)));
typedef short s16x8 __attribute__((ext_vector_type(8)));
typedef _Float16 f16x2 __attribute__((ext_vector_type(2)));

__device__ inline short f2bf(float x) {
    __hip_bfloat16 h = __float2bfloat16(x);
    return __builtin_bit_cast(short, h);
}

// Truncating pack: 2 f32 -> u32 {bf16(hi),bf16(lo)}. One v_perm_b32.
__device__ inline unsigned pk_trunc(float hi, float lo) {
    return __builtin_amdgcn_perm(__builtin_bit_cast(unsigned, hi),
                                 __builtin_bit_cast(unsigned, lo),
                                 0x07060302u);
}
// Packed relu on 2 bf16 via v_pk_max_f16. Sign-compare vs +0 is format-agnostic;
// our magnitudes (<2^121) never alias f16 NaN. -0/denorm edge -> ~1e-38, harmless.
__device__ inline unsigned pk_relu(unsigned x) {
    f16x2 v = __builtin_bit_cast(f16x2, x);
    f16x2 z = {(_Float16)0.f, (_Float16)0.f};
    return __builtin_bit_cast(unsigned, __builtin_elementwise_max(v, z));
}
__device__ inline float rfl(float x) {
    return __builtin_bit_cast(float, __builtin_amdgcn_readfirstlane(__builtin_bit_cast(int, x)));
}

// ---- 16x16x16 bf16 MFMA: builtin if present, else inline asm ----
#if defined(__has_builtin)
#  if __has_builtin(__builtin_amdgcn_mfma_f32_16x16x16bf16_1k)
#    define MFMA16(a, b, c) __builtin_amdgcn_mfma_f32_16x16x16bf16_1k((a), (b), (c), 0, 0, 0)
#    define HAVE_MFMA16 1
#  elif __has_builtin(__builtin_amdgcn_mfma_f32_16x16x16_bf16)
#    define MFMA16(a, b, c) __builtin_amdgcn_mfma_f32_16x16x16_bf16((a), (b), (c), 0, 0, 0)
#    define HAVE_MFMA16 1
#  endif
#endif
#ifndef HAVE_MFMA16
__device__ inline f32x4 mfma16_asm(s16x4 a, s16x4 b, f32x4 c) {
    asm volatile("s_nop 1\n\tv_mfma_f32_16x16x16_bf16 %0, %1, %2, %0"
                 : "+v"(c) : "v"(a), "v"(b));
    return c;
}
#  define MFMA16(a, b, c) mfma16_asm((a), (b), (c))
#endif

#if defined(__has_builtin) && __has_builtin(__builtin_amdgcn_global_load_lds)
#  define HAVE_GLDS 1
#endif

// ---------------------------------------------------------------------------
// Kernel A/D: 64->64->64 MLP + per-group partial stats.
// extra>0: inp has (extra+1) slices of N*64 to be summed on load.
// ---------------------------------------------------------------------------
__global__ __launch_bounds__(256) void mlp_gn_kernel(
    const float* __restrict__ inp, int extra,
    const float* __restrict__ W1, const float* __restrict__ b1,
    const float* __restrict__ W2, const float* __restrict__ b2,
    float* __restrict__ pre_out, float* __restrict__ partials)
{
    __shared__ float in_s[4][64];
    __shared__ float h1_s[4][64];
    __shared__ float red_s[4][8];

    const int tid = threadIdx.x;
    const int lane = tid & 63;
    const int wid = tid >> 6;
    const int n0 = blockIdx.x * 4;

    float xin = inp[n0 * 64 + tid];
    for (int s = 1; s <= extra; ++s)
        xin += inp[(size_t)s * (N_PTS * 64) + n0 * 64 + tid];
    in_s[wid][lane] = xin;
    __syncthreads();

    const int c = lane;
    float h = b1[c];
#pragma unroll
    for (int k4 = 0; k4 < 16; ++k4) {
        float4 wv = *(const float4*)&W1[c * 64 + k4 * 4];
        h = fmaf(in_s[wid][k4*4+0], wv.x, h);
        h = fmaf(in_s[wid][k4*4+1], wv.y, h);
        h = fmaf(in_s[wid][k4*4+2], wv.z, h);
        h = fmaf(in_s[wid][k4*4+3], wv.w, h);
    }
    h = (h >= 0.f) ? h : 0.2f * h;
    h1_s[wid][c] = h;
    __syncthreads();

    float g = b2[c];
#pragma unroll
    for (int k4 = 0; k4 < 16; ++k4) {
        float4 wv = *(const float4*)&W2[c * 64 + k4 * 4];
        g = fmaf(h1_s[wid][k4*4+0], wv.x, g);
        g = fmaf(h1_s[wid][k4*4+1], wv.y, g);
        g = fmaf(h1_s[wid][k4*4+2], wv.z, g);
        g = fmaf(h1_s[wid][k4*4+3], wv.w, g);
    }
    g = (g >= 0.f) ? g : 0.2f * g;
    pre_out[n0 * 64 + tid] = g;

    float v = g, v2 = g * g;
#pragma unroll
    for (int m = 1; m < 16; m <<= 1) {
        v  += __shfl_xor(v,  m, 64);
        v2 += __shfl_xor(v2, m, 64);
    }
    if ((lane & 15) == 0) {
        int grp = lane >> 4;
        red_s[wid][grp * 2 + 0] = v;
        red_s[wid][grp * 2 + 1] = v2;
    }
    __syncthreads();
    if (tid < 8) {
        int grp = tid >> 1, which = tid & 1;
        float s = red_s[0][grp*2+which] + red_s[1][grp*2+which]
                + red_s[2][grp*2+which] + red_s[3][grp*2+which];
        partials[blockIdx.x * 8 + grp * 2 + which] = s;
    }
}

// ---------------------------------------------------------------------------
// Kernel B/E: finalize group stats -> per-channel scale/shift.
// ---------------------------------------------------------------------------
__global__ __launch_bounds__(256) void finalize_kernel(
    const float* __restrict__ partials, int nblocks,
    const float* __restrict__ gw, const float* __restrict__ gb,
    float* __restrict__ ss)
{
    __shared__ float red[8][32];
    __shared__ float mean_s[4], inv_s[4];
    const int t = threadIdx.x;
    const int s = t >> 5, slot = t & 31;
    float acc = 0.f;
    for (int b = slot; b < nblocks; b += 32) acc += partials[b * 8 + s];
    red[s][slot] = acc;
    __syncthreads();
    if (t < 8) {
        float v = 0.f;
#pragma unroll
        for (int k = 0; k < 32; ++k) v += red[t][k];
        red[t][0] = v;
    }
    __syncthreads();
    if (t < 4) {
        float S = red[t * 2][0], SS = red[t * 2 + 1][0];
        const float cnt = (float)N_PTS * 16.f;
        float mean = S / cnt;
        float var = SS / cnt - mean * mean;
        mean_s[t] = mean;
        inv_s[t] = rsqrtf(var + 1e-5f);
    }
    __syncthreads();
    if (t < 64) {
        int grp = t >> 4;
        float sc = gw[t] * inv_s[grp];
        ss[t] = sc;
        ss[64 + t] = gb[t] - mean_s[grp] * sc;
    }
}

// ---------------------------------------------------------------------------
// fnt: normalized features bf16, pre-swizzled per 64-j tile for b128 reads:
//   jj=j&63: jsub=jj>>4, g=(jj>>2)&3, r=jj&3; u=g*4+jsub; p=u>>1; lo=u&1;
//   pos = h*64 + (p^(h&7))*8 + lo*4 + r
// Also (blocks 0..15) scaled coords + normal, f32 padded.
// ---------------------------------------------------------------------------
__global__ __launch_bounds__(256) void fnt_kernel(
    const float* __restrict__ f_pre, const float* __restrict__ ss,
    short* __restrict__ fn_sw,
    const float* __restrict__ points, const float* __restrict__ nuv,
    float* __restrict__ ptn4)
{
    const int h = blockIdx.x >> 4;
    const int j = ((blockIdx.x & 15) << 8) + threadIdx.x;
    float v = f_pre[j * 64 + h] * ss[h] + ss[64 + h];
    const int t = j >> 6, jj = j & 63;
    const int jsub = jj >> 4, g = (jj >> 2) & 3, r = jj & 3;
    const int u = g * 4 + jsub, p = u >> 1, lo = u & 1;
    const int pp = p ^ (h & 7);
    fn_sw[t * 4096 + h * 64 + pp * 8 + lo * 4 + r] = f2bf(v);

    if (blockIdx.x < 16) {
        const int pt = blockIdx.x * 256 + threadIdx.x;
        float sx = points[pt*3+0] * INV_SQRT2;
        float sy = points[pt*3+1] * INV_SQRT2;
        float sz = points[pt*3+2] * INV_SQRT2;
        float nx = nuv[pt*9+0], ny = nuv[pt*9+1], nz = nuv[pt*9+2];
        *(float4*)&ptn4[pt*8 + 0] = (float4){sx, sy, sz, 0.f};
        *(float4*)&ptn4[pt*8 + 4] = (float4){nx, ny, nz, 0.f};
    }
}

// ---------------------------------------------------------------------------
// Pairwise: 4 waves/block, EACH WAVE OWNS 2 i's (block = 8 i's); fn fragment
// reads shared across the 2 i's. j-split JS (runtime 2 or 4), nt tiles/block.
// ---------------------------------------------------------------------------
__global__ __launch_bounds__(256, 4) void pairwise_kernel(
    const float* __restrict__ nuv,
    const float* __restrict__ ptn4,
    const short* __restrict__ fn_sw,
    const float* __restrict__ A1, const float* __restrict__ c1,
    const float* __restrict__ A2, const float* __restrict__ c2,
    float* __restrict__ out_part, int nt, int jshift)
{
    __shared__ __align__(16) short FS[2][4096];        // 16 KB dbuf
    __shared__ __align__(16) short P_s[8][64*12 + 16]; // 12.25 KB (4 waves x 2 i)

    const int tid = threadIdx.x;
    const int l = tid & 63;
    const int wid = tid >> 6;
    const int g = l >> 4;
    const int hl = l & 15;

    const int js = blockIdx.x & ((1 << jshift) - 1);
    const int ig = blockIdx.x >> jshift;
    const int i0 = ig * 8 + wid * 2;
    const int jbase = js * nt * 64;
    const int tmask = nt - 1;

    // ---- i-side constants -> SGPRs via readfirstlane ----
    float s_nv[2][9], s_pi[2][3];
#pragma unroll
    for (int ii = 0; ii < 2; ++ii) {
#pragma unroll
        for (int k = 0; k < 9; ++k) s_nv[ii][k] = rfl(nuv[(i0 + ii) * 9 + k]);
#pragma unroll
        for (int k = 0; k < 3; ++k) s_pi[ii][k] = rfl(ptn4[(i0 + ii) * 8 + k]);
    }
    float a1v[8][3], c1v[8];
#pragma unroll
    for (int cc = 0; cc < 8; ++cc) {
        a1v[cc][0] = A1[cc*3+0]; a1v[cc][1] = A1[cc*3+1]; a1v[cc][2] = A1[cc*3+2];
        c1v[cc] = c1[cc];
    }

    // A2t B-frags (K=16): lane(g,hl): B[k=4g+r][h=ht*16+hl] = A2[h][k]|c2|0
    s16x4 A2sB[4];
#pragma unroll
    for (int ht = 0; ht < 4; ++ht) {
        const int h = ht * 16 + hl;
        s16x4 v;
#pragma unroll
        for (int r = 0; r < 4; ++r) {
            const int cc = 4 * g + r;
            float val = (cc < 8) ? A2[h*8 + cc] : ((cc == 8) ? c2[h] : 0.f);
            v[r] = f2bf(val);
        }
        A2sB[ht] = v;
    }

    f32x4 acc0[4], acc1[4];
#pragma unroll
    for (int ht = 0; ht < 4; ++ht) {
        acc0[ht] = (f32x4){0.f, 0.f, 0.f, 0.f};
        acc1[ht] = (f32x4){0.f, 0.f, 0.f, 0.f};
    }

    // loop-invariant FS read offsets (bytes): row hl, 16B unit (2g+jp)^(hl&7)
    const char* FSb = (const char*)&FS[0][0];
    const int fs_off0 = hl * 128 + ((((g << 1) | 0) ^ (hl & 7)) << 4);
    const int fs_off1 = hl * 128 + ((((g << 1) | 1) ^ (hl & 7)) << 4);

    auto stage = [&](int buf, int t) {
        const short* src = fn_sw + (size_t)(js * nt + t) * 4096;
#ifdef HAVE_GLDS
        const short* s0 = src + wid * 1024 + l * 8;
        short* d0 = &FS[buf][wid * 1024];
        __builtin_amdgcn_global_load_lds((const unsigned int*)s0,
                                         (unsigned int*)d0, 16, 0, 0);
        __builtin_amdgcn_global_load_lds((const unsigned int*)(s0 + 512),
                                         (unsigned int*)(d0 + 512), 16, 0, 0);
#else
        s16x8 a = *(const s16x8*)(src + tid * 16);
        s16x8 b = *(const s16x8*)(src + tid * 16 + 8);
        *(s16x8*)&FS[buf][tid * 16] = a;
        *(s16x8*)&FS[buf][tid * 16 + 8] = b;
#endif
    };

    const float* pbase = ptn4 + (size_t)jbase * 8;
    float4 pj_c = *(const float4*)&pbase[l * 8];
    float4 nj_c = *(const float4*)&pbase[l * 8 + 4];
    stage(0, 0);

    auto tile = [&](const int t, const int cur) {
        __syncthreads();                        // FS[cur] staged; FS[cur^1] free
        if (t < nt - 1) stage(cur ^ 1, t + 1);  // async to other buffer

        const int tn = (t + 1) & tmask;
        float4 pj_n = *(const float4*)&pbase[(tn * 64 + l) * 8];
        float4 nj_n = *(const float4*)&pbase[(tn * 64 + l) * 8 + 4];

        // ---- phase 1: lane l owns j = jbase + t*64 + l, for both i's ----
#pragma unroll
        for (int ii = 0; ii < 2; ++ii) {
            float dx = pj_c.x - s_pi[ii][0];
            float dy = pj_c.y - s_pi[ii][1];
            float dz = pj_c.z - s_pi[ii][2];
            float s1 = dx*dx + dy*dy + dz*dz;
            float dot = s_nv[ii][0]*nj_c.x + s_nv[ii][1]*nj_c.y + s_nv[ii][2]*nj_c.z;
            float t2v = 2.f - dot;
            float d2 = s1 * t2v * t2v;
            float w = __expf(-d2);
            float X0 = s_nv[ii][0]*dx + s_nv[ii][1]*dy + s_nv[ii][2]*dz;
            float X1 = s_nv[ii][3]*dx + s_nv[ii][4]*dy + s_nv[ii][5]*dz;
            float X2 = s_nv[ii][6]*dx + s_nv[ii][7]*dy + s_nv[ii][8]*dz;

            float hv[8];
#pragma unroll
            for (int cc = 0; cc < 8; ++cc) {
                float tt = fmaf(X0, a1v[cc][0],
                           fmaf(X1, a1v[cc][1],
                           fmaf(X2, a1v[cc][2], c1v[cc])));
                hv[cc] = tt * w;                 // relu deferred to packed max
            }
            int2 ra, rb, rc;
            ra.x = (int)pk_relu(pk_trunc(hv[1], hv[0]));
            ra.y = (int)pk_relu(pk_trunc(hv[3], hv[2]));
            rb.x = (int)pk_relu(pk_trunc(hv[5], hv[4]));
            rb.y = (int)pk_relu(pk_trunc(hv[7], hv[6]));
            rc.x = (int)(__builtin_bit_cast(unsigned, w) >> 16);  // {w, 0}
            rc.y = 0;
            short* rp = &P_s[wid * 2 + ii][l * 12];
            *(int2*)(rp + 0) = ra;
            *(int2*)(rp + 4) = rb;
            *(int2*)(rp + 8) = rc;
        }
        // no barrier: P_s is wave-local.

        // ---- phase 2 ----
#pragma unroll
        for (int jp = 0; jp < 2; ++jp) {
            s16x8 F[4];
            const int fo = (jp == 0) ? fs_off0 : fs_off1;
#pragma unroll
            for (int ht = 0; ht < 4; ++ht)
                F[ht] = *(const s16x8*)(FSb + cur * 8192 + ht * 2048 + fo);
#pragma unroll
            for (int lo = 0; lo < 2; ++lo) {
                const int jsub = jp * 2 + lo;
                const s16x4 Af0 = *(const s16x4*)&P_s[wid*2+0][(jsub*16 + hl)*12 + 4*g];
                const s16x4 Af1 = *(const s16x4*)&P_s[wid*2+1][(jsub*16 + hl)*12 + 4*g];
#pragma unroll
                for (int ht = 0; ht < 4; ++ht) {
                    const s16x4 fnf = lo
                        ? __builtin_shufflevector(F[ht], F[ht], 4, 5, 6, 7)
                        : __builtin_shufflevector(F[ht], F[ht], 0, 1, 2, 3);
                    f32x4 Z0 = MFMA16(Af0, A2sB[ht], ((f32x4){0.f,0.f,0.f,0.f}));
                    int2 a0;
                    a0.x = (int)pk_relu(pk_trunc(Z0[1], Z0[0]));
                    a0.y = (int)pk_relu(pk_trunc(Z0[3], Z0[2]));
                    acc0[ht] = MFMA16(fnf, __builtin_bit_cast(s16x4, a0), acc0[ht]);
                    f32x4 Z1 = MFMA16(Af1, A2sB[ht], ((f32x4){0.f,0.f,0.f,0.f}));
                    int2 a1;
                    a1.x = (int)pk_relu(pk_trunc(Z1[1], Z1[0]));
                    a1.y = (int)pk_relu(pk_trunc(Z1[3], Z1[2]));
                    acc1[ht] = MFMA16(fnf, __builtin_bit_cast(s16x4, a1), acc1[ht]);
                }
            }
        }
        pj_c = pj_n; nj_c = nj_n;
    };

    for (int tp = 0; tp < nt; tp += 2) {
        tile(tp, 0);
        tile(tp + 1, 1);
    }

    asm volatile("s_nop 7\n\ts_nop 7" ::: );

    // diag extraction: lane with g == hl>>2 holds diag element (reg r = hl&3)
    if (g == (hl >> 2)) {
        const int r = hl & 3;
        float* ob = out_part + (size_t)js * (N_PTS * 64);
#pragma unroll
        for (int ht = 0; ht < 4; ++ht) {
            float v0 = (r == 0) ? acc0[ht][0] : (r == 1) ? acc0[ht][1]
                     : (r == 2) ? acc0[ht][2] : acc0[ht][3];
            float v1 = (r == 0) ? acc1[ht][0] : (r == 1) ? acc1[ht][1]
                     : (r == 2) ? acc1[ht][2] : acc1[ht][3];
            ob[(i0 + 0) * 64 + ht * 16 + hl] = v0;
            ob[(i0 + 1) * 64 + ht * 16 + hl] = v1;
        }
    }
}

// ---------------------------------------------------------------------------
// Kernel F: apply output groupnorm affine.
// ---------------------------------------------------------------------------
__global__ __launch_bounds__(256) void apply_kernel(
    const float* __restrict__ pre, const float* __restrict__ ss,
    float* __restrict__ out)
{
    int idx = blockIdx.x * 256 + threadIdx.x;
    int c = idx & 63;
    out[idx] = pre[idx] * ss[c] + ss[64 + c];
}

// ---------------------------------------------------------------------------
extern "C" void kernel_launch(void* const* d_in, const int* in_sizes, int n_in,
                              void* d_out, int out_size, void* d_ws, size_t ws_size,
                              hipStream_t stream) {
    const float* points   = (const float*)d_in[0];
    const float* nuv      = (const float*)d_in[1];
    const float* features = (const float*)d_in[2];
    const float* W_in1    = (const float*)d_in[3];
    const float* b_in1    = (const float*)d_in[4];
    const float* W_in2    = (const float*)d_in[5];
    const float* b_in2    = (const float*)d_in[6];
    const float* gn_in_w  = (const float*)d_in[7];
    const float* gn_in_b  = (const float*)d_in[8];
    const float* A1       = (const float*)d_in[9];
    const float* c1       = (const float*)d_in[10];
    const float* A2       = (const float*)d_in[11];
    const float* c2       = (const float*)d_in[12];
    const float* W_out1   = (const float*)d_in[13];
    const float* b_out1   = (const float*)d_in[14];
    const float* W_out2   = (const float*)d_in[15];
    const float* b_out2   = (const float*)d_in[16];
    const float* gn_out_w = (const float*)d_in[17];
    const float* gn_out_b = (const float*)d_in[18];

    // j-split: 4 if workspace allows (4MB partials), else 2 (proven-safe size).
    const size_t MB = 1048576;
    const int JS = (ws_size >= 5 * MB) ? 4 : 2;
    const int jshift = (JS == 4) ? 2 : 1;
    const int nt = 64 / JS;
    const size_t op_bytes = (size_t)JS * N_PTS * 64 * 4;

    char* ws = (char*)d_ws;
    float* out_part = (float*)(ws + 0);                 // JS MB
    float* f_pre    = (float*)(ws + 0);                 // 1 MB alias (dead early)
    float* g_pre    = (float*)(ws + 0);                 // 1 MB alias (late, safe)
    short* fn_sw    = (short*)(ws + op_bytes);          // 512 KB
    float* ptn4     = (float*)(ws + op_bytes + 524288); // 128 KB
    char*  tail     = ws + op_bytes + 524288 + 131072;
    float* part_in  = (float*)(tail);                   // 32 KB
    float* part_out = (float*)(tail + 32768);           // 32 KB
    float* ss_in    = (float*)(tail + 65536);           // 512 B
    float* ss_out   = (float*)(tail + 66048);           // 512 B

    float* outp = (float*)d_out;

    mlp_gn_kernel<<<1024, 256, 0, stream>>>(features, 0, W_in1, b_in1,
                                            W_in2, b_in2, f_pre, part_in);
    finalize_kernel<<<1, 256, 0, stream>>>(part_in, 1024, gn_in_w, gn_in_b, ss_in);
    fnt_kernel<<<1024, 256, 0, stream>>>(f_pre, ss_in, fn_sw, points, nuv, ptn4);

    pairwise_kernel<<<512 * JS, 256, 0, stream>>>(nuv, ptn4, fn_sw,
                                                  A1, c1, A2, c2, out_part,
                                                  nt, jshift);

    mlp_gn_kernel<<<1024, 256, 0, stream>>>(out_part, JS - 1, W_out1, b_out1,
                                            W_out2, b_out2, g_pre, part_out);
    finalize_kernel<<<1, 256, 0, stream>>>(part_out, 1024, gn_out_w, gn_out_b, ss_out);

    apply_kernel<<<1024, 256, 0, stream>>>(g_pre, ss_out, outp);
}